// Round 13
// baseline (377.357 us; speedup 1.0000x reference)
//
#include <hip/hip_runtime.h>

#define B 8
#define N 2048
#define D 64
#define BN (B*N)
#define CAP 64
#define NBLK_L 2048

// ---- node A: proj (blocks 0..255) + streaming scan (blocks 256..2303) ----
// Scan reads the 128 MB adjacency in PURE memory order (copy-bench pattern):
// wave-chunk W = 64 consecutive float4s (1 KB). Columns chunk*256+lane*4+c,
// row j = (W>>3)&2047, b = W>>14.  __ballot packs 64 lanes' predicates into
// u64 row-direction masks; lanes 0-3 write the 4 component masks to rowtile.
__global__ __launch_bounds__(256) void kA(
        const float* __restrict__ adj, const float* __restrict__ x,
        const float* __restrict__ U0, const float* __restrict__ b0,
        unsigned long long* __restrict__ rowtile, float* __restrict__ h0,
        int* __restrict__ done) {
    __shared__ float Uld[D * D];
    __shared__ float bld[D];
    const int tid = threadIdx.x, bid = blockIdx.x;
    const int wid = tid >> 6, lane = tid & 63;
    if (bid == 0 && tid == 0) *done = 0;       // reset ticket for this launch
    if (bid < 256) {
        // ---- proj: h0 = x @ U0 + b0, 16 rows/wave ----
#pragma unroll
        for (int q = 0; q < 16; ++q) Uld[tid + q * 256] = U0[tid + q * 256];
        if (tid < D) bld[tid] = b0[tid];
        __syncthreads();
        int gw = bid * 4 + wid;                // wave id [0, 1024)
        for (int rr = 0; rr < 16; ++rr) {
            int r = gw * 16 + rr;              // row [0, 16384)
            float xv = x[(size_t)r * D + lane];
            float o0 = bld[lane], o1 = 0.f, o2 = 0.f, o3 = 0.f;
#pragma unroll
            for (int k = 0; k < D; k += 4) {
                o0 = fmaf(__shfl(xv, k),     Uld[(k)     * D + lane], o0);
                o1 = fmaf(__shfl(xv, k + 1), Uld[(k + 1) * D + lane], o1);
                o2 = fmaf(__shfl(xv, k + 2), Uld[(k + 2) * D + lane], o2);
                o3 = fmaf(__shfl(xv, k + 3), Uld[(k + 3) * D + lane], o3);
            }
            h0[(size_t)r * D + lane] = (o0 + o1) + (o2 + o3);
        }
    } else {
        // ---- streaming scan: 8192 waves x 16 chunks, fully contiguous ----
        int gw = (bid - 256) * 4 + wid;        // wave id [0, 8192)
        for (int t = 0; t < 16; ++t) {
            unsigned W = t * 8192 + gw;        // wave-chunk [0, 131072)
            unsigned chunk = W & 7;
            unsigned j = (W >> 3) & 2047;
            unsigned b = W >> 14;
            float4 v = ((const float4*)adj)[(size_t)W * 64 + lane];
            unsigned long long m0 = __ballot(v.x != 0.f);
            unsigned long long m1 = __ballot(v.y != 0.f);
            unsigned long long m2 = __ballot(v.z != 0.f);
            unsigned long long m3 = __ballot(v.w != 0.f);
            unsigned long long mv = lane == 0 ? m0 : lane == 1 ? m1
                                  : lane == 2 ? m2 : m3;
            unsigned plane = (b * 8 + chunk) * 4;
            if (lane < 4)
                rowtile[(size_t)(plane + lane) * 2048 + j] = mv;
        }
    }
}

// ---- node B: bit-plane transpose -> per-column lists + degree ----
// 256 blocks x 64 thr.  Block = plane (b, chunk, c): 16 KB of u64 row-masks.
// Bulk-load plane to LDS (coalesced), then thread l extracts column
// chunk*256 + l*4 + c by testing bit l of each row word (LDS broadcast).
__global__ __launch_bounds__(64) void kB(
        const unsigned long long* __restrict__ rowtile,
        unsigned short* __restrict__ cols, int* __restrict__ cnt) {
    __shared__ unsigned long long pl[2048];    // 16 KB
    const int l = threadIdx.x;
    const int p = blockIdx.x;                  // plane [0, 256)
#pragma unroll
    for (int it = 0; it < 32; ++it)
        pl[it * 64 + l] = rowtile[(size_t)p * 2048 + it * 64 + l];
    __syncthreads();
    int b = p >> 5, chunk = (p >> 2) & 7, c = p & 3;
    int gcol = b * N + chunk * 256 + l * 4 + c;
    unsigned short* cl = cols + (size_t)gcol * CAP;
    const unsigned* pl32 = (const unsigned*)pl;
    int hi = (l >> 5) & 1, sh = l & 31;
    int cv = 0;
#pragma unroll 8
    for (int j = 0; j < 2048; ++j) {
        unsigned m = pl32[j * 2 + hi];         // 2 addrs/wave -> free broadcast
        if ((m >> sh) & 1u) {
            if (cv < CAP) cl[cv] = (unsigned short)j;
            ++cv;
        }
    }
    cnt[gcol] = cv;                            // exact degree (adj is {0,1})
}

// ---- GCN layer (R10 structure + index mask).  2048 blocks x 256 thr,
// 2 rows/wave, 16 gathers in flight.  Last layer (pg != nullptr) also writes
// pg partials and the last-finished block computes the head (ticket). ----
__global__ __launch_bounds__(256) void kL(const float* __restrict__ hin,
        const unsigned short* __restrict__ cols, const int* __restrict__ cnt,
        const float* __restrict__ U, float* __restrict__ hout,
        float* __restrict__ pg, const float* __restrict__ Q,
        const float* __restrict__ P, float* __restrict__ out,
        int* __restrict__ done) {
    __shared__ float Uld[D * D];
    __shared__ float part[4][D];
    __shared__ int lastf;
    const int tid = threadIdx.x;
    const int bid = blockIdx.x;
#pragma unroll
    for (int q = 0; q < 16; ++q) Uld[tid + q * 256] = U[tid + q * 256];
    __syncthreads();
    int wid = tid >> 6, lane = tid & 63;
    int r0 = bid * 8 + wid * 2, r1 = r0 + 1;
    const float* hb = hin + ((size_t)(r0 >> 11) << 11) * D;   // batch base
    int ca = cnt[r0], cb = cnt[r1];
    int kma = ca < CAP ? ca : CAP, kmb = cb < CAP ? cb : CAP;
    const unsigned short* la = cols + (size_t)r0 * CAP;
    const unsigned short* lb = cols + (size_t)r1 * CAP;
    float acca = 0.f, accb = 0.f;
    int km = kma > kmb ? kma : kmb;
    for (int k = 0; k < km; k += 8) {          // 16 gathers in flight
        uint4 wa = *(const uint4*)(la + k);
        uint4 wb = *(const uint4*)(lb + k);
        float a0 = hb[(size_t)(wa.x & 0x7ff)         * D + lane];
        float a1 = hb[(size_t)((wa.x >> 16) & 0x7ff) * D + lane];
        float a2 = hb[(size_t)(wa.y & 0x7ff)         * D + lane];
        float a3 = hb[(size_t)((wa.y >> 16) & 0x7ff) * D + lane];
        float a4 = hb[(size_t)(wa.z & 0x7ff)         * D + lane];
        float a5 = hb[(size_t)((wa.z >> 16) & 0x7ff) * D + lane];
        float a6 = hb[(size_t)(wa.w & 0x7ff)         * D + lane];
        float a7 = hb[(size_t)((wa.w >> 16) & 0x7ff) * D + lane];
        float b0_ = hb[(size_t)(wb.x & 0x7ff)         * D + lane];
        float b1_ = hb[(size_t)((wb.x >> 16) & 0x7ff) * D + lane];
        float b2_ = hb[(size_t)(wb.y & 0x7ff)         * D + lane];
        float b3_ = hb[(size_t)((wb.y >> 16) & 0x7ff) * D + lane];
        float b4_ = hb[(size_t)(wb.z & 0x7ff)         * D + lane];
        float b5_ = hb[(size_t)((wb.z >> 16) & 0x7ff) * D + lane];
        float b6_ = hb[(size_t)(wb.w & 0x7ff)         * D + lane];
        float b7_ = hb[(size_t)((wb.w >> 16) & 0x7ff) * D + lane];
        acca += ((k + 0 < kma ? a0 : 0.f) + (k + 1 < kma ? a1 : 0.f))
              + ((k + 2 < kma ? a2 : 0.f) + (k + 3 < kma ? a3 : 0.f))
              + ((k + 4 < kma ? a4 : 0.f) + (k + 5 < kma ? a5 : 0.f))
              + ((k + 6 < kma ? a6 : 0.f) + (k + 7 < kma ? a7 : 0.f));
        accb += ((k + 0 < kmb ? b0_ : 0.f) + (k + 1 < kmb ? b1_ : 0.f))
              + ((k + 2 < kmb ? b2_ : 0.f) + (k + 3 < kmb ? b3_ : 0.f))
              + ((k + 4 < kmb ? b4_ : 0.f) + (k + 5 < kmb ? b5_ : 0.f))
              + ((k + 6 < kmb ? b6_ : 0.f) + (k + 7 < kmb ? b7_ : 0.f));
    }
    float oa0 = 0.f, oa1 = 0.f, oa2 = 0.f, oa3 = 0.f;
    float ob0 = 0.f, ob1 = 0.f, ob2 = 0.f, ob3 = 0.f;
#pragma unroll
    for (int d = 0; d < D; d += 4) {           // 8 independent fma chains
        oa0 = fmaf(__shfl(acca, d),     Uld[(d)     * D + lane], oa0);
        ob0 = fmaf(__shfl(accb, d),     Uld[(d)     * D + lane], ob0);
        oa1 = fmaf(__shfl(acca, d + 1), Uld[(d + 1) * D + lane], oa1);
        ob1 = fmaf(__shfl(accb, d + 1), Uld[(d + 1) * D + lane], ob1);
        oa2 = fmaf(__shfl(acca, d + 2), Uld[(d + 2) * D + lane], oa2);
        ob2 = fmaf(__shfl(accb, d + 2), Uld[(d + 2) * D + lane], ob2);
        oa3 = fmaf(__shfl(acca, d + 3), Uld[(d + 3) * D + lane], oa3);
        ob3 = fmaf(__shfl(accb, d + 3), Uld[(d + 3) * D + lane], ob3);
    }
    float outa = fmaxf(((oa0 + oa1) + (oa2 + oa3)) / (float)ca, 0.f);
    float outb = fmaxf(((ob0 + ob1) + (ob2 + ob3)) / (float)cb, 0.f);
    hout[(size_t)r0 * D + lane] = outa;
    hout[(size_t)r1 * D + lane] = outb;
    if (pg != nullptr) {
        part[wid][lane] = outa + outb;
        __syncthreads();
        if (wid == 0)
            pg[(size_t)bid * D + lane] =
                part[0][lane] + part[1][lane] + part[2][lane] + part[3][lane];
        __threadfence();                       // make pg visible device-wide
        if (tid == 0) lastf = (atomicAdd(done, 1) == NBLK_L - 1);
        __syncthreads();
        if (lastf) {                           // last block computes the head
#pragma unroll
            for (int q = 0; q < 2; ++q) {
                int bb = wid * 2 + q;          // wave handles 2 batches
                float md = 0.f;
#pragma unroll 8
                for (int k = 0; k < 256; ++k)
                    md += pg[(size_t)(bb * 256 + k) * D + lane];
                md *= (1.0f / N);              // m[bb][lane]
                float t = 0.f;
#pragma unroll 8
                for (int k = 0; k < D; ++k)
                    t = fmaf(Q[lane * D + k], __shfl(md, k), t);
                t = fmaxf(t, 0.f);
                float v = t * P[lane];
                for (int o = 32; o; o >>= 1) v += __shfl_down(v, o);
                if (lane == 0) out[bb] = v;
            }
        }
    }
}

extern "C" void kernel_launch(void* const* d_in, const int* in_sizes, int n_in,
                              void* d_out, int out_size, void* d_ws, size_t ws_size,
                              hipStream_t stream) {
    const float* x   = (const float*)d_in[0];
    const float* adj = (const float*)d_in[1];
    const float* U0  = (const float*)d_in[2];
    const float* b0  = (const float*)d_in[3];
    const float* Us  = (const float*)d_in[4];
    const float* Q   = (const float*)d_in[5];
    const float* P   = (const float*)d_in[6];
    float* out = (float*)d_out;

    char* ws = (char*)d_ws;
    size_t off = 0;
    float* h0 = (float*)(ws + off); off += (size_t)BN * D * sizeof(float);  // 4 MB
    float* h1 = (float*)(ws + off); off += (size_t)BN * D * sizeof(float);  // 4 MB
    unsigned short* cols = (unsigned short*)(ws + off);
    off += (size_t)CAP * BN * sizeof(unsigned short);                       // 2 MB
    int* cnt = (int*)(ws + off); off += (size_t)BN * sizeof(int);           // 64 KB
    float* pg = (float*)(ws + off); off += (size_t)NBLK_L * D * sizeof(float); // 512 KB
    int* done = (int*)(ws + off); off += 64;

    // rowtile aliases h1 (exactly 4 MB): consumed by kB before L1 writes h1.
    unsigned long long* rowtile = (unsigned long long*)h1;

    kA<<<2304, 256, 0, stream>>>(adj, x, U0, b0, rowtile, h0, done);
    kB<<<256, 64, 0, stream>>>(rowtile, cols, cnt);
    kL<<<NBLK_L, 256, 0, stream>>>(h0, cols, cnt, Us + 0 * D * D, h1,
                                   nullptr, nullptr, nullptr, nullptr, nullptr);
    kL<<<NBLK_L, 256, 0, stream>>>(h1, cols, cnt, Us + 1 * D * D, h0,
                                   nullptr, nullptr, nullptr, nullptr, nullptr);
    kL<<<NBLK_L, 256, 0, stream>>>(h0, cols, cnt, Us + 2 * D * D, h1,
                                   pg, Q, P, out, done);
}

// Round 14
// 236.648 us; speedup vs baseline: 1.5946x; 1.5946x over previous
//
#include <hip/hip_runtime.h>

#define B 8
#define N 2048
#define D 64
#define BN (B*N)
#define CAP 64

// ---- node A: proj (blocks 0..255) + streaming scan (blocks 256..2303) ----
// Scan reads the 128 MB adjacency in PURE memory order (copy-bench pattern):
// wave-chunk W = 64 consecutive float4s (1 KB). Column chunk*256+lane*4+c,
// row j = (W>>3)&2047, b = W>>14.  __ballot packs 64 lanes' predicates into
// u64 row-direction masks; lanes 0-3 write the 4 component masks to rowtile.
__global__ __launch_bounds__(256) void kA(
        const float* __restrict__ adj, const float* __restrict__ x,
        const float* __restrict__ U0, const float* __restrict__ b0,
        unsigned long long* __restrict__ rowtile, float* __restrict__ h0) {
    __shared__ float Uld[D * D];
    __shared__ float bld[D];
    const int tid = threadIdx.x, bid = blockIdx.x;
    const int wid = tid >> 6, lane = tid & 63;
    if (bid < 256) {
        // ---- proj: h0 = x @ U0 + b0, 16 rows/wave ----
#pragma unroll
        for (int q = 0; q < 16; ++q) Uld[tid + q * 256] = U0[tid + q * 256];
        if (tid < D) bld[tid] = b0[tid];
        __syncthreads();
        int gw = bid * 4 + wid;                // wave id [0, 1024)
        for (int rr = 0; rr < 16; ++rr) {
            int r = gw * 16 + rr;              // row [0, 16384)
            float xv = x[(size_t)r * D + lane];
            float o0 = bld[lane], o1 = 0.f, o2 = 0.f, o3 = 0.f;
#pragma unroll
            for (int k = 0; k < D; k += 4) {
                o0 = fmaf(__shfl(xv, k),     Uld[(k)     * D + lane], o0);
                o1 = fmaf(__shfl(xv, k + 1), Uld[(k + 1) * D + lane], o1);
                o2 = fmaf(__shfl(xv, k + 2), Uld[(k + 2) * D + lane], o2);
                o3 = fmaf(__shfl(xv, k + 3), Uld[(k + 3) * D + lane], o3);
            }
            h0[(size_t)r * D + lane] = (o0 + o1) + (o2 + o3);
        }
    } else {
        // ---- streaming scan: 8192 waves x 16 chunks, fully contiguous ----
        int gw = (bid - 256) * 4 + wid;        // wave id [0, 8192)
        for (int t = 0; t < 16; ++t) {
            unsigned W = t * 8192 + gw;        // wave-chunk [0, 131072)
            unsigned chunk = W & 7;
            unsigned j = (W >> 3) & 2047;
            unsigned b = W >> 14;
            float4 v = ((const float4*)adj)[(size_t)W * 64 + lane];
            unsigned long long m0 = __ballot(v.x != 0.f);
            unsigned long long m1 = __ballot(v.y != 0.f);
            unsigned long long m2 = __ballot(v.z != 0.f);
            unsigned long long m3 = __ballot(v.w != 0.f);
            unsigned long long mv = lane == 0 ? m0 : lane == 1 ? m1
                                  : lane == 2 ? m2 : m3;
            unsigned plane = (b * 8 + chunk) * 4;
            if (lane < 4)
                rowtile[(size_t)(plane + lane) * 2048 + j] = mv;
        }
    }
}

// ---- node B: bit-plane transpose -> per-column lists + degree ----
// 256 blocks x 64 thr.  Block = plane (b, chunk, c): 16 KB of u64 row-masks.
// Bulk-load plane to LDS (coalesced), then thread l extracts column
// chunk*256 + l*4 + c by testing bit l of each row word (LDS broadcast).
__global__ __launch_bounds__(64) void kB(
        const unsigned long long* __restrict__ rowtile,
        unsigned short* __restrict__ cols, int* __restrict__ cnt) {
    __shared__ unsigned long long pl[2048];    // 16 KB
    const int l = threadIdx.x;
    const int p = blockIdx.x;                  // plane [0, 256)
#pragma unroll
    for (int it = 0; it < 32; ++it)
        pl[it * 64 + l] = rowtile[(size_t)p * 2048 + it * 64 + l];
    __syncthreads();
    int b = p >> 5, chunk = (p >> 2) & 7, c = p & 3;
    int gcol = b * N + chunk * 256 + l * 4 + c;
    unsigned short* cl = cols + (size_t)gcol * CAP;
    const unsigned* pl32 = (const unsigned*)pl;
    int hi = (l >> 5) & 1, sh = l & 31;
    int cv = 0;
#pragma unroll 8
    for (int j = 0; j < 2048; ++j) {
        unsigned m = pl32[j * 2 + hi];         // 2 addrs/wave -> free broadcast
        if ((m >> sh) & 1u) {
            if (cv < CAP) cl[cv] = (unsigned short)j;
            ++cv;
        }
    }
    cnt[gcol] = cv;                            // exact degree (adj is {0,1})
}

// ---- GCN layer: EXACT R11 structure.  2 rows/wave, 16 gathers in flight +
// carried next-batch index prefetch (forces allocator to keep batch live).
// 2048 blocks x 256 thr; block owns rows bid*8..+7.  Indices masked to
// [0,2048); stale tail values discarded by predication.
// If pg != nullptr also writes pg[bid][d] = sum of this block's 8 output rows.
__global__ __launch_bounds__(256) void kL(const float* __restrict__ hin,
        const unsigned short* __restrict__ cols, const int* __restrict__ cnt,
        const float* __restrict__ U, float* __restrict__ hout,
        float* __restrict__ pg) {
    __shared__ float Uld[D * D];
    __shared__ float part[4][D];
    const int tid = threadIdx.x;
    const int bid = blockIdx.x;
#pragma unroll
    for (int q = 0; q < 16; ++q) Uld[tid + q * 256] = U[tid + q * 256];
    __syncthreads();
    int wid = tid >> 6, lane = tid & 63;
    int r0 = bid * 8 + wid * 2, r1 = r0 + 1;
    const float* hb = hin + ((size_t)(r0 >> 11) << 11) * D;   // batch base
    int ca = cnt[r0], cb = cnt[r1];
    int kma = ca < CAP ? ca : CAP, kmb = cb < CAP ? cb : CAP;
    const unsigned short* la = cols + (size_t)r0 * CAP;
    const unsigned short* lb = cols + (size_t)r1 * CAP;
    float acca = 0.f, accb = 0.f;
    int km = kma > kmb ? kma : kmb;
    uint4 wa = *(const uint4*)(la);
    uint4 wb = *(const uint4*)(lb);
    for (int k = 0; k < km; k += 8) {
        // prefetch next batch's indices (overrun stays inside cols/cnt ws)
        uint4 na = *(const uint4*)(la + k + 8);
        uint4 nb = *(const uint4*)(lb + k + 8);
        float a0 = hb[(size_t)(wa.x & 0x7ff)         * D + lane];
        float a1 = hb[(size_t)((wa.x >> 16) & 0x7ff) * D + lane];
        float a2 = hb[(size_t)(wa.y & 0x7ff)         * D + lane];
        float a3 = hb[(size_t)((wa.y >> 16) & 0x7ff) * D + lane];
        float a4 = hb[(size_t)(wa.z & 0x7ff)         * D + lane];
        float a5 = hb[(size_t)((wa.z >> 16) & 0x7ff) * D + lane];
        float a6 = hb[(size_t)(wa.w & 0x7ff)         * D + lane];
        float a7 = hb[(size_t)((wa.w >> 16) & 0x7ff) * D + lane];
        float b0_ = hb[(size_t)(wb.x & 0x7ff)         * D + lane];
        float b1_ = hb[(size_t)((wb.x >> 16) & 0x7ff) * D + lane];
        float b2_ = hb[(size_t)(wb.y & 0x7ff)         * D + lane];
        float b3_ = hb[(size_t)((wb.y >> 16) & 0x7ff) * D + lane];
        float b4_ = hb[(size_t)(wb.z & 0x7ff)         * D + lane];
        float b5_ = hb[(size_t)((wb.z >> 16) & 0x7ff) * D + lane];
        float b6_ = hb[(size_t)(wb.w & 0x7ff)         * D + lane];
        float b7_ = hb[(size_t)((wb.w >> 16) & 0x7ff) * D + lane];
        acca += ((k + 0 < kma ? a0 : 0.f) + (k + 1 < kma ? a1 : 0.f))
              + ((k + 2 < kma ? a2 : 0.f) + (k + 3 < kma ? a3 : 0.f))
              + ((k + 4 < kma ? a4 : 0.f) + (k + 5 < kma ? a5 : 0.f))
              + ((k + 6 < kma ? a6 : 0.f) + (k + 7 < kma ? a7 : 0.f));
        accb += ((k + 0 < kmb ? b0_ : 0.f) + (k + 1 < kmb ? b1_ : 0.f))
              + ((k + 2 < kmb ? b2_ : 0.f) + (k + 3 < kmb ? b3_ : 0.f))
              + ((k + 4 < kmb ? b4_ : 0.f) + (k + 5 < kmb ? b5_ : 0.f))
              + ((k + 6 < kmb ? b6_ : 0.f) + (k + 7 < kmb ? b7_ : 0.f));
        wa = na; wb = nb;
    }
    float oa0 = 0.f, oa1 = 0.f, oa2 = 0.f, oa3 = 0.f;
    float ob0 = 0.f, ob1 = 0.f, ob2 = 0.f, ob3 = 0.f;
#pragma unroll
    for (int d = 0; d < D; d += 4) {           // 8 independent fma chains
        oa0 = fmaf(__shfl(acca, d),     Uld[(d)     * D + lane], oa0);
        ob0 = fmaf(__shfl(accb, d),     Uld[(d)     * D + lane], ob0);
        oa1 = fmaf(__shfl(acca, d + 1), Uld[(d + 1) * D + lane], oa1);
        ob1 = fmaf(__shfl(accb, d + 1), Uld[(d + 1) * D + lane], ob1);
        oa2 = fmaf(__shfl(acca, d + 2), Uld[(d + 2) * D + lane], oa2);
        ob2 = fmaf(__shfl(accb, d + 2), Uld[(d + 2) * D + lane], ob2);
        oa3 = fmaf(__shfl(acca, d + 3), Uld[(d + 3) * D + lane], oa3);
        ob3 = fmaf(__shfl(accb, d + 3), Uld[(d + 3) * D + lane], ob3);
    }
    float outa = fmaxf(((oa0 + oa1) + (oa2 + oa3)) / (float)ca, 0.f);
    float outb = fmaxf(((ob0 + ob1) + (ob2 + ob3)) / (float)cb, 0.f);
    hout[(size_t)r0 * D + lane] = outa;
    hout[(size_t)r1 * D + lane] = outb;
    if (pg != nullptr) {
        part[wid][lane] = outa + outb;
        __syncthreads();
        if (wid == 0)
            pg[(size_t)bid * D + lane] =
                part[0][lane] + part[1][lane] + part[2][lane] + part[3][lane];
    }
}

// ---- head: 1 block x 512; wave w = batch w reduces its 256 pg partials ----
__global__ __launch_bounds__(512) void kHead(const float* __restrict__ pg,
        const float* __restrict__ Q, const float* __restrict__ P,
        float* __restrict__ out) {
    int wid = threadIdx.x >> 6, lane = threadIdx.x & 63;
    float md = 0.f;
#pragma unroll 8
    for (int k = 0; k < 256; ++k) md += pg[(size_t)(wid * 256 + k) * D + lane];
    md *= (1.0f / N);                           // m[b][lane]
    float t = 0.f;
#pragma unroll 8
    for (int k = 0; k < D; ++k) t = fmaf(Q[lane * D + k], __shfl(md, k), t);
    t = fmaxf(t, 0.f);
    float v = t * P[lane];
    for (int off = 32; off; off >>= 1) v += __shfl_down(v, off);
    if (lane == 0) out[wid] = v;
}

extern "C" void kernel_launch(void* const* d_in, const int* in_sizes, int n_in,
                              void* d_out, int out_size, void* d_ws, size_t ws_size,
                              hipStream_t stream) {
    const float* x   = (const float*)d_in[0];
    const float* adj = (const float*)d_in[1];
    const float* U0  = (const float*)d_in[2];
    const float* b0  = (const float*)d_in[3];
    const float* Us  = (const float*)d_in[4];
    const float* Q   = (const float*)d_in[5];
    const float* P   = (const float*)d_in[6];
    float* out = (float*)d_out;

    char* ws = (char*)d_ws;
    size_t off = 0;
    float* h0 = (float*)(ws + off); off += (size_t)BN * D * sizeof(float);  // 4 MB
    float* h1 = (float*)(ws + off); off += (size_t)BN * D * sizeof(float);  // 4 MB
    unsigned short* cols = (unsigned short*)(ws + off);
    off += (size_t)CAP * BN * sizeof(unsigned short);                       // 2 MB
    int* cnt = (int*)(ws + off); off += (size_t)BN * sizeof(int);           // 64 KB
    float* pg = (float*)(ws + off); off += (size_t)2048 * D * sizeof(float); // 512 KB

    // rowtile aliases h1 (exactly 4 MB): consumed by kB before L0 writes h1.
    unsigned long long* rowtile = (unsigned long long*)h1;

    kA<<<2304, 256, 0, stream>>>(adj, x, U0, b0, rowtile, h0);
    kB<<<256, 64, 0, stream>>>(rowtile, cols, cnt);
    kL<<<2048, 256, 0, stream>>>(h0, cols, cnt, Us + 0 * D * D, h1, nullptr);
    kL<<<2048, 256, 0, stream>>>(h1, cols, cnt, Us + 1 * D * D, h0, nullptr);
    kL<<<2048, 256, 0, stream>>>(h0, cols, cnt, Us + 2 * D * D, h1, pg);
    kHead<<<1, 512, 0, stream>>>(pg, Q, P, out);
}

// Round 15
// 116.325 us; speedup vs baseline: 3.2440x; 2.0344x over previous
//
#include <hip/hip_runtime.h>

#define B 8
#define N 2048
#define D 64
#define BN (B*N)
#define CAP 64

// ---- node 1: scan -> lists (+ proj).  R10-proven.  512 blocks x 256 thr.
// blocks [0,256): block = (b, ck) owns 64 columns over full j range; thread =
//   (j-octave jb = tid>>5, col-pair cp = tid&31), float2 loads; column masks
//   in LDS (thread-disjoint), 64 threads extract lists + exact degree.
// blocks [256,512): h0 = x @ U0 + b0, 16 rows/wave.
__global__ __launch_bounds__(256) void kSLP(
        const float* __restrict__ adj, const float* __restrict__ x,
        const float* __restrict__ U0, const float* __restrict__ b0,
        unsigned short* __restrict__ cols, int* __restrict__ cnt,
        float* __restrict__ h0) {
    __shared__ unsigned sh[64 * 65 + 64];      // 16.9 KB, aliased by both paths
    const int tid = threadIdx.x;
    const int bid = blockIdx.x;
    if (bid < 256) {
        unsigned (*lmask)[65] = (unsigned(*)[65])sh;   // [64 cols][64 words +pad]
        int b  = bid >> 5, ck = bid & 31;
        int jb = tid >> 5;                     // j octave: rows jb*256 .. +255
        int cp = tid & 31;                     // col pair within chunk
        int c0 = cp * 2, c1 = cp * 2 + 1;
        const float* base = adj + (size_t)b * N * N + (size_t)(jb * 256) * N
                            + ck * 64 + cp * 2;
        for (int ws = 0; ws < 8; ++ws) {       // 8 words per octave
            unsigned w0 = 0, w1 = 0;
#pragma unroll 8
            for (int i = 0; i < 32; ++i) {     // j = jb*256 + ws*32 + i
                float2 v = *(const float2*)(base + (size_t)(ws * 32 + i) * N);
                w0 |= (v.x != 0.f ? 1u : 0u) << i;
                w1 |= (v.y != 0.f ? 1u : 0u) << i;
            }
            lmask[c0][jb * 8 + ws] = w0;       // thread-disjoint words
            lmask[c1][jb * 8 + ws] = w1;
        }
        __syncthreads();
        if (tid < 64) {                        // extract lists, j ascending
            int gcol = b * N + ck * 64 + tid;
            unsigned short* cl = cols + (size_t)gcol * CAP;
            int p = 0;
            for (int w = 0; w < 64; ++w) {
                unsigned m = lmask[tid][w];
                int jbase = w * 32;
                while (m) {
                    int t = __builtin_ctz(m);
                    m &= m - 1;
                    if (p < CAP) cl[p] = (unsigned short)(jbase + t);
                    ++p;
                }
            }
            cnt[gcol] = p;                     // exact degree (adj is {0,1})
        }
    } else {
        float* Uld = (float*)sh;               // 4096 floats
        float* bld = (float*)(sh + 4096);      // 64 floats
#pragma unroll
        for (int q = 0; q < 16; ++q) Uld[tid + q * 256] = U0[tid + q * 256];
        if (tid < D) bld[tid] = b0[tid];
        __syncthreads();
        int wid = tid >> 6, lane = tid & 63;
        int gw = (bid - 256) * 4 + wid;        // wave id [0, 1024)
        for (int rr = 0; rr < 16; ++rr) {
            int r = gw * 16 + rr;              // row [0, 16384)
            float xv = x[(size_t)r * D + lane];
            float o0 = bld[lane], o1 = 0.f, o2 = 0.f, o3 = 0.f;
#pragma unroll
            for (int k = 0; k < D; k += 4) {
                o0 = fmaf(__shfl(xv, k),     Uld[(k)     * D + lane], o0);
                o1 = fmaf(__shfl(xv, k + 1), Uld[(k + 1) * D + lane], o1);
                o2 = fmaf(__shfl(xv, k + 2), Uld[(k + 2) * D + lane], o2);
                o3 = fmaf(__shfl(xv, k + 3), Uld[(k + 3) * D + lane], o3);
            }
            h0[(size_t)r * D + lane] = (o0 + o1) + (o2 + o3);
        }
    }
}

// ---- GCN layer (R12 body): 4 rows/wave -> 32 gathers + 4 carried index
// prefetches in flight.  1024 blocks x 256 thr; block owns rows bid*16..+15.
// Indices masked to [0,2048); stale tail values discarded by predication.
// If pg != nullptr also writes pg[bid][d] = sum of this block's 16 output rows.
__global__ __launch_bounds__(256) void kL(const float* __restrict__ hin,
        const unsigned short* __restrict__ cols, const int* __restrict__ cnt,
        const float* __restrict__ U, float* __restrict__ hout,
        float* __restrict__ pg) {
    __shared__ float Uld[D * D];
    __shared__ float part[4][D];
    const int tid = threadIdx.x;
    const int bid = blockIdx.x;
#pragma unroll
    for (int q = 0; q < 16; ++q) Uld[tid + q * 256] = U[tid + q * 256];
    __syncthreads();
    int wid = tid >> 6, lane = tid & 63;
    int rbase = bid * 16 + wid * 4;
    const float* hb = hin + ((size_t)(rbase >> 11) << 11) * D;   // batch base
    int c[4], kmx[4];
    const unsigned short* cl[4];
#pragma unroll
    for (int q = 0; q < 4; ++q) {
        int r = rbase + q;
        c[q] = cnt[r];
        kmx[q] = c[q] < CAP ? c[q] : CAP;
        cl[q] = cols + (size_t)r * CAP;
    }
    int km01 = kmx[0] > kmx[1] ? kmx[0] : kmx[1];
    int km23 = kmx[2] > kmx[3] ? kmx[2] : kmx[3];
    int km = km01 > km23 ? km01 : km23;
    float acc[4] = {0.f, 0.f, 0.f, 0.f};
    uint4 w4[4];
#pragma unroll
    for (int q = 0; q < 4; ++q) w4[q] = *(const uint4*)(cl[q]);
    for (int k = 0; k < km; k += 8) {
        uint4 nx[4];
#pragma unroll
        for (int q = 0; q < 4; ++q) nx[q] = *(const uint4*)(cl[q] + k + 8);
#pragma unroll
        for (int q = 0; q < 4; ++q) {
            float a0 = hb[(size_t)(w4[q].x & 0x7ff)         * D + lane];
            float a1 = hb[(size_t)((w4[q].x >> 16) & 0x7ff) * D + lane];
            float a2 = hb[(size_t)(w4[q].y & 0x7ff)         * D + lane];
            float a3 = hb[(size_t)((w4[q].y >> 16) & 0x7ff) * D + lane];
            float a4 = hb[(size_t)(w4[q].z & 0x7ff)         * D + lane];
            float a5 = hb[(size_t)((w4[q].z >> 16) & 0x7ff) * D + lane];
            float a6 = hb[(size_t)(w4[q].w & 0x7ff)         * D + lane];
            float a7 = hb[(size_t)((w4[q].w >> 16) & 0x7ff) * D + lane];
            acc[q] += ((k + 0 < kmx[q] ? a0 : 0.f) + (k + 1 < kmx[q] ? a1 : 0.f))
                    + ((k + 2 < kmx[q] ? a2 : 0.f) + (k + 3 < kmx[q] ? a3 : 0.f))
                    + ((k + 4 < kmx[q] ? a4 : 0.f) + (k + 5 < kmx[q] ? a5 : 0.f))
                    + ((k + 6 < kmx[q] ? a6 : 0.f) + (k + 7 < kmx[q] ? a7 : 0.f));
        }
#pragma unroll
        for (int q = 0; q < 4; ++q) w4[q] = nx[q];
    }
    float rsum = 0.f;
#pragma unroll
    for (int q = 0; q < 4; ++q) {
        float o0 = 0.f, o1 = 0.f, o2 = 0.f, o3 = 0.f;
#pragma unroll
        for (int d = 0; d < D; d += 4) {       // 4 independent fma chains
            o0 = fmaf(__shfl(acc[q], d),     Uld[(d)     * D + lane], o0);
            o1 = fmaf(__shfl(acc[q], d + 1), Uld[(d + 1) * D + lane], o1);
            o2 = fmaf(__shfl(acc[q], d + 2), Uld[(d + 2) * D + lane], o2);
            o3 = fmaf(__shfl(acc[q], d + 3), Uld[(d + 3) * D + lane], o3);
        }
        float ov = fmaxf(((o0 + o1) + (o2 + o3)) / (float)c[q], 0.f);
        hout[(size_t)(rbase + q) * D + lane] = ov;
        rsum += ov;
    }
    if (pg != nullptr) {
        part[wid][lane] = rsum;
        __syncthreads();
        if (wid == 0)
            pg[(size_t)bid * D + lane] =
                part[0][lane] + part[1][lane] + part[2][lane] + part[3][lane];
    }
}

// ---- head: 1 block x 512; wave w = batch w reduces its 128 pg partials ----
__global__ __launch_bounds__(512) void kHead(const float* __restrict__ pg,
        const float* __restrict__ Q, const float* __restrict__ P,
        float* __restrict__ out) {
    int wid = threadIdx.x >> 6, lane = threadIdx.x & 63;
    float md = 0.f;
#pragma unroll 8
    for (int k = 0; k < 128; ++k) md += pg[(size_t)(wid * 128 + k) * D + lane];
    md *= (1.0f / N);                           // m[b][lane]
    float t = 0.f;
#pragma unroll 8
    for (int k = 0; k < D; ++k) t = fmaf(Q[lane * D + k], __shfl(md, k), t);
    t = fmaxf(t, 0.f);
    float v = t * P[lane];
    for (int off = 32; off; off >>= 1) v += __shfl_down(v, off);
    if (lane == 0) out[wid] = v;
}

extern "C" void kernel_launch(void* const* d_in, const int* in_sizes, int n_in,
                              void* d_out, int out_size, void* d_ws, size_t ws_size,
                              hipStream_t stream) {
    const float* x   = (const float*)d_in[0];
    const float* adj = (const float*)d_in[1];
    const float* U0  = (const float*)d_in[2];
    const float* b0  = (const float*)d_in[3];
    const float* Us  = (const float*)d_in[4];
    const float* Q   = (const float*)d_in[5];
    const float* P   = (const float*)d_in[6];
    float* out = (float*)d_out;

    char* ws = (char*)d_ws;
    size_t off = 0;
    float* h0 = (float*)(ws + off); off += (size_t)BN * D * sizeof(float);  // 4 MB
    float* h1 = (float*)(ws + off); off += (size_t)BN * D * sizeof(float);  // 4 MB
    unsigned short* cols = (unsigned short*)(ws + off);
    off += (size_t)CAP * BN * sizeof(unsigned short);                       // 2 MB
    int* cnt = (int*)(ws + off); off += (size_t)BN * sizeof(int);           // 64 KB
    float* pg = (float*)(ws + off); off += (size_t)1024 * D * sizeof(float); // 256 KB

    kSLP<<<512, 256, 0, stream>>>(adj, x, U0, b0, cols, cnt, h0);
    kL<<<1024, 256, 0, stream>>>(h0, cols, cnt, Us + 0 * D * D, h1, nullptr);
    kL<<<1024, 256, 0, stream>>>(h1, cols, cnt, Us + 1 * D * D, h0, nullptr);
    kL<<<1024, 256, 0, stream>>>(h0, cols, cnt, Us + 2 * D * D, h1, pg);
    kHead<<<1, 512, 0, stream>>>(pg, Q, P, out);
}

// Round 16
// 110.066 us; speedup vs baseline: 3.4285x; 1.0569x over previous
//
#include <hip/hip_runtime.h>

#define B 8
#define N 2048
#define D 64
#define BN (B*N)
#define CAP 64

// ---- node 1: scan -> lists (+ proj).  512 blocks x 256 thr.
// blocks [0,256): block = (b, ck) owns 64 columns over full j range; thread =
//   (col-quad cq = tid&15, j-segment js = tid>>4 of 128 rows), float4 loads
//   (wave = 4 x 256B segments = 1 KB/load-instr, 128 loads/thread); column
//   masks in LDS (thread-disjoint words), 64 threads extract lists + degree.
// blocks [256,512): h0 = x @ U0 + b0, 16 rows/wave.
__global__ __launch_bounds__(256) void kSLP(
        const float* __restrict__ adj, const float* __restrict__ x,
        const float* __restrict__ U0, const float* __restrict__ b0,
        unsigned short* __restrict__ cols, int* __restrict__ cnt,
        float* __restrict__ h0) {
    __shared__ unsigned sh[64 * 65 + 64];      // 16.9 KB, aliased by both paths
    const int tid = threadIdx.x;
    const int bid = blockIdx.x;
    if (bid < 256) {
        unsigned (*lmask)[65] = (unsigned(*)[65])sh;   // [64 cols][64 words +pad]
        int b  = bid >> 5, ck = bid & 31;
        int cq = tid & 15;                     // col quad: cols ck*64+cq*4 ..+3
        int js = tid >> 4;                     // j segment [0,16): rows js*128..+127
        const float* base = adj + (size_t)b * N * N + (size_t)(js * 128) * N
                            + ck * 64 + cq * 4;
        for (int w = 0; w < 4; ++w) {          // 4 words of 32 rows each
            unsigned m0 = 0, m1 = 0, m2 = 0, m3 = 0;
#pragma unroll 8
            for (int i = 0; i < 32; ++i) {     // j = js*128 + w*32 + i
                float4 v = *(const float4*)(base + (size_t)(w * 32 + i) * N);
                m0 |= (v.x != 0.f ? 1u : 0u) << i;
                m1 |= (v.y != 0.f ? 1u : 0u) << i;
                m2 |= (v.z != 0.f ? 1u : 0u) << i;
                m3 |= (v.w != 0.f ? 1u : 0u) << i;
            }
            int wIdx = js * 4 + w;             // word index: j_base = wIdx*32
            lmask[cq * 4 + 0][wIdx] = m0;      // thread-disjoint words
            lmask[cq * 4 + 1][wIdx] = m1;
            lmask[cq * 4 + 2][wIdx] = m2;
            lmask[cq * 4 + 3][wIdx] = m3;
        }
        __syncthreads();
        if (tid < 64) {                        // extract lists, j ascending
            int gcol = b * N + ck * 64 + tid;
            unsigned short* cl = cols + (size_t)gcol * CAP;
            int p = 0;
            for (int w = 0; w < 64; ++w) {
                unsigned m = lmask[tid][w];
                int jbase = w * 32;
                while (m) {
                    int t = __builtin_ctz(m);
                    m &= m - 1;
                    if (p < CAP) cl[p] = (unsigned short)(jbase + t);
                    ++p;
                }
            }
            cnt[gcol] = p;                     // exact degree (adj is {0,1})
        }
    } else {
        float* Uld = (float*)sh;               // 4096 floats
        float* bld = (float*)(sh + 4096);      // 64 floats
#pragma unroll
        for (int q = 0; q < 16; ++q) Uld[tid + q * 256] = U0[tid + q * 256];
        if (tid < D) bld[tid] = b0[tid];
        __syncthreads();
        int wid = tid >> 6, lane = tid & 63;
        int gw = (bid - 256) * 4 + wid;        // wave id [0, 1024)
        for (int rr = 0; rr < 16; ++rr) {
            int r = gw * 16 + rr;              // row [0, 16384)
            float xv = x[(size_t)r * D + lane];
            float o0 = bld[lane], o1 = 0.f, o2 = 0.f, o3 = 0.f;
#pragma unroll
            for (int k = 0; k < D; k += 4) {
                o0 = fmaf(__shfl(xv, k),     Uld[(k)     * D + lane], o0);
                o1 = fmaf(__shfl(xv, k + 1), Uld[(k + 1) * D + lane], o1);
                o2 = fmaf(__shfl(xv, k + 2), Uld[(k + 2) * D + lane], o2);
                o3 = fmaf(__shfl(xv, k + 3), Uld[(k + 3) * D + lane], o3);
            }
            h0[(size_t)r * D + lane] = (o0 + o1) + (o2 + o3);
        }
    }
}

// ---- GCN layer (R14-proven): 2 rows/wave, 16 gathers in flight + carried
// next-batch index prefetch.  2048 blocks x 256 thr; block owns rows bid*8..+7.
// Indices masked to [0,2048); stale tail values discarded by predication.
// If pg != nullptr also writes pg[bid][d] = sum of this block's 8 output rows.
__global__ __launch_bounds__(256) void kL(const float* __restrict__ hin,
        const unsigned short* __restrict__ cols, const int* __restrict__ cnt,
        const float* __restrict__ U, float* __restrict__ hout,
        float* __restrict__ pg) {
    __shared__ float Uld[D * D];
    __shared__ float part[4][D];
    const int tid = threadIdx.x;
    const int bid = blockIdx.x;
#pragma unroll
    for (int q = 0; q < 16; ++q) Uld[tid + q * 256] = U[tid + q * 256];
    __syncthreads();
    int wid = tid >> 6, lane = tid & 63;
    int r0 = bid * 8 + wid * 2, r1 = r0 + 1;
    const float* hb = hin + ((size_t)(r0 >> 11) << 11) * D;   // batch base
    int ca = cnt[r0], cb = cnt[r1];
    int kma = ca < CAP ? ca : CAP, kmb = cb < CAP ? cb : CAP;
    const unsigned short* la = cols + (size_t)r0 * CAP;
    const unsigned short* lb = cols + (size_t)r1 * CAP;
    float acca = 0.f, accb = 0.f;
    int km = kma > kmb ? kma : kmb;
    uint4 wa = *(const uint4*)(la);
    uint4 wb = *(const uint4*)(lb);
    for (int k = 0; k < km; k += 8) {
        // prefetch next batch's indices (overrun stays inside cols/cnt ws)
        uint4 na = *(const uint4*)(la + k + 8);
        uint4 nb = *(const uint4*)(lb + k + 8);
        float a0 = hb[(size_t)(wa.x & 0x7ff)         * D + lane];
        float a1 = hb[(size_t)((wa.x >> 16) & 0x7ff) * D + lane];
        float a2 = hb[(size_t)(wa.y & 0x7ff)         * D + lane];
        float a3 = hb[(size_t)((wa.y >> 16) & 0x7ff) * D + lane];
        float a4 = hb[(size_t)(wa.z & 0x7ff)         * D + lane];
        float a5 = hb[(size_t)((wa.z >> 16) & 0x7ff) * D + lane];
        float a6 = hb[(size_t)(wa.w & 0x7ff)         * D + lane];
        float a7 = hb[(size_t)((wa.w >> 16) & 0x7ff) * D + lane];
        float b0_ = hb[(size_t)(wb.x & 0x7ff)         * D + lane];
        float b1_ = hb[(size_t)((wb.x >> 16) & 0x7ff) * D + lane];
        float b2_ = hb[(size_t)(wb.y & 0x7ff)         * D + lane];
        float b3_ = hb[(size_t)((wb.y >> 16) & 0x7ff) * D + lane];
        float b4_ = hb[(size_t)(wb.z & 0x7ff)         * D + lane];
        float b5_ = hb[(size_t)((wb.z >> 16) & 0x7ff) * D + lane];
        float b6_ = hb[(size_t)(wb.w & 0x7ff)         * D + lane];
        float b7_ = hb[(size_t)((wb.w >> 16) & 0x7ff) * D + lane];
        acca += ((k + 0 < kma ? a0 : 0.f) + (k + 1 < kma ? a1 : 0.f))
              + ((k + 2 < kma ? a2 : 0.f) + (k + 3 < kma ? a3 : 0.f))
              + ((k + 4 < kma ? a4 : 0.f) + (k + 5 < kma ? a5 : 0.f))
              + ((k + 6 < kma ? a6 : 0.f) + (k + 7 < kma ? a7 : 0.f));
        accb += ((k + 0 < kmb ? b0_ : 0.f) + (k + 1 < kmb ? b1_ : 0.f))
              + ((k + 2 < kmb ? b2_ : 0.f) + (k + 3 < kmb ? b3_ : 0.f))
              + ((k + 4 < kmb ? b4_ : 0.f) + (k + 5 < kmb ? b5_ : 0.f))
              + ((k + 6 < kmb ? b6_ : 0.f) + (k + 7 < kmb ? b7_ : 0.f));
        wa = na; wb = nb;
    }
    float oa0 = 0.f, oa1 = 0.f, oa2 = 0.f, oa3 = 0.f;
    float ob0 = 0.f, ob1 = 0.f, ob2 = 0.f, ob3 = 0.f;
#pragma unroll
    for (int d = 0; d < D; d += 4) {           // 8 independent fma chains
        oa0 = fmaf(__shfl(acca, d),     Uld[(d)     * D + lane], oa0);
        ob0 = fmaf(__shfl(accb, d),     Uld[(d)     * D + lane], ob0);
        oa1 = fmaf(__shfl(acca, d + 1), Uld[(d + 1) * D + lane], oa1);
        ob1 = fmaf(__shfl(accb, d + 1), Uld[(d + 1) * D + lane], ob1);
        oa2 = fmaf(__shfl(acca, d + 2), Uld[(d + 2) * D + lane], oa2);
        ob2 = fmaf(__shfl(accb, d + 2), Uld[(d + 2) * D + lane], ob2);
        oa3 = fmaf(__shfl(acca, d + 3), Uld[(d + 3) * D + lane], oa3);
        ob3 = fmaf(__shfl(accb, d + 3), Uld[(d + 3) * D + lane], ob3);
    }
    float outa = fmaxf(((oa0 + oa1) + (oa2 + oa3)) / (float)ca, 0.f);
    float outb = fmaxf(((ob0 + ob1) + (ob2 + ob3)) / (float)cb, 0.f);
    hout[(size_t)r0 * D + lane] = outa;
    hout[(size_t)r1 * D + lane] = outb;
    if (pg != nullptr) {
        part[wid][lane] = outa + outb;
        __syncthreads();
        if (wid == 0)
            pg[(size_t)bid * D + lane] =
                part[0][lane] + part[1][lane] + part[2][lane] + part[3][lane];
    }
}

// ---- head: 1 block x 512; wave w = batch w reduces its 256 pg partials ----
__global__ __launch_bounds__(512) void kHead(const float* __restrict__ pg,
        const float* __restrict__ Q, const float* __restrict__ P,
        float* __restrict__ out) {
    int wid = threadIdx.x >> 6, lane = threadIdx.x & 63;
    float md = 0.f;
#pragma unroll 8
    for (int k = 0; k < 256; ++k) md += pg[(size_t)(wid * 256 + k) * D + lane];
    md *= (1.0f / N);                           // m[b][lane]
    float t = 0.f;
#pragma unroll 8
    for (int k = 0; k < D; ++k) t = fmaf(Q[lane * D + k], __shfl(md, k), t);
    t = fmaxf(t, 0.f);
    float v = t * P[lane];
    for (int off = 32; off; off >>= 1) v += __shfl_down(v, off);
    if (lane == 0) out[wid] = v;
}

extern "C" void kernel_launch(void* const* d_in, const int* in_sizes, int n_in,
                              void* d_out, int out_size, void* d_ws, size_t ws_size,
                              hipStream_t stream) {
    const float* x   = (const float*)d_in[0];
    const float* adj = (const float*)d_in[1];
    const float* U0  = (const float*)d_in[2];
    const float* b0  = (const float*)d_in[3];
    const float* Us  = (const float*)d_in[4];
    const float* Q   = (const float*)d_in[5];
    const float* P   = (const float*)d_in[6];
    float* out = (float*)d_out;

    char* ws = (char*)d_ws;
    size_t off = 0;
    float* h0 = (float*)(ws + off); off += (size_t)BN * D * sizeof(float);  // 4 MB
    float* h1 = (float*)(ws + off); off += (size_t)BN * D * sizeof(float);  // 4 MB
    unsigned short* cols = (unsigned short*)(ws + off);
    off += (size_t)CAP * BN * sizeof(unsigned short);                       // 2 MB
    int* cnt = (int*)(ws + off); off += (size_t)BN * sizeof(int);           // 64 KB
    float* pg = (float*)(ws + off); off += (size_t)2048 * D * sizeof(float); // 512 KB

    kSLP<<<512, 256, 0, stream>>>(adj, x, U0, b0, cols, cnt, h0);
    kL<<<2048, 256, 0, stream>>>(h0, cols, cnt, Us + 0 * D * D, h1, nullptr);
    kL<<<2048, 256, 0, stream>>>(h1, cols, cnt, Us + 1 * D * D, h0, nullptr);
    kL<<<2048, 256, 0, stream>>>(h0, cols, cnt, Us + 2 * D * D, h1, pg);
    kHead<<<1, 512, 0, stream>>>(pg, Q, P, out);
}